// Round 3
// baseline (795.484 us; speedup 1.0000x reference)
//
#include <hip/hip_runtime.h>
#include <math.h>

#define T_    4
#define B_    32
#define C_    64
#define CO_   64
#define N_    4096
#define K_    8
#define PL_   3
#define TB_   128          // T_*B_
#define TN_   256          // n-tile per conv block
#define NT_   16           // N_/TN_
#define NBLK_ 2048         // TB_*NT_
#define CCH_  16           // ci chunk staged in LDS at a time
#define ROWW_ (TN_ + 8)    // padded LDS row (264 floats); only 263 used

// ---------------------------------------------------------------------------
// Kernel 1: conv1d (bias cancels in BN) + per-(block,channel) BN partials.
// One block = one tb row x 256-wide n tile x all 64 co. Wave wv owns co
// [wv*16, wv*16+16); weight addresses are wave-uniform -> scalar s_loads.
// LDS stages 16 input channels at a time; next chunk is prefetched into
// registers during compute (hides global latency; barriers stay cheap).
// FMA chain per (co,n): ci ascending, k ascending -- BITWISE IDENTICAL to
// rounds 1/2 (absmax 0.0). Do not reassociate.
// ---------------------------------------------------------------------------
__global__ __launch_bounds__(256, 4)
void conv_stats_kernel(const float* __restrict__ x, const float* __restrict__ w,
                       float* __restrict__ y, float* __restrict__ psum)
{
    __shared__ float xs[CCH_][ROWW_];   // 16 x 264 floats = 16.9 KB

    const int bx   = blockIdx.x;
    const int tb   = bx >> 4;           // 0..127
    const int n0   = (bx & 15) * TN_;   // n tile origin
    const int tid  = threadIdx.x;
    const int lane = tid & 63;
    const int cg   = __builtin_amdgcn_readfirstlane(tid >> 6) * 16;  // wave co base
    const int noff = lane * 4;          // lane's n offset inside tile

    // staging coords: thread owns row ci_s, columns i = i0 + 16*s (s=0..16)
    const int ci_s = tid >> 4;          // 0..15
    const int i0   = tid & 15;          // 0..15

    float acc[16][4];
#pragma unroll
    for (int i = 0; i < 16; ++i)
#pragma unroll
        for (int j = 0; j < 4; ++j) acc[i][j] = 0.0f;

    const float* xrow = x + (size_t)tb * C_ * N_;

    // ---- prologue: load chunk 0 into regs, store to LDS ----
    float pf[17];
#pragma unroll
    for (int s = 0; s < 17; ++s) {
        int i = i0 + 16 * s;
        int n = n0 - PL_ + i;
        float v = 0.0f;
        if (i < TN_ + 7 && n >= 0 && n < N_) v = xrow[(size_t)ci_s * N_ + n];
        pf[s] = v;
    }
#pragma unroll
    for (int s = 0; s < 17; ++s) {
        int i = i0 + 16 * s;
        if (i < TN_ + 7) xs[ci_s][i] = pf[s];
    }
    __syncthreads();

    for (int cc = 0; cc < C_ / CCH_; ++cc) {
        // ---- issue prefetch of chunk cc+1 (overlaps compute below) ----
        if (cc < C_ / CCH_ - 1) {
            const float* xnext = xrow + (size_t)(cc + 1) * CCH_ * N_;
#pragma unroll
            for (int s = 0; s < 17; ++s) {
                int i = i0 + 16 * s;
                int n = n0 - PL_ + i;
                float v = 0.0f;
                if (i < TN_ + 7 && n >= 0 && n < N_) v = xnext[(size_t)ci_s * N_ + n];
                pf[s] = v;
            }
        }

        // ---- compute on chunk cc ----
        for (int ci2 = 0; ci2 < CCH_; ++ci2) {
            const int ci = cc * CCH_ + ci2;
            const float4* xp = (const float4*)(&xs[ci2][noff]);
            float4 xa = xp[0], xb = xp[1], xc = xp[2];
            float xr[12] = {xa.x, xa.y, xa.z, xa.w,
                            xb.x, xb.y, xb.z, xb.w,
                            xc.x, xc.y, xc.z, xc.w};
            const float* wp = w + ((size_t)cg * C_ + ci) * K_;
#pragma unroll
            for (int coi = 0; coi < 16; ++coi) {
                const float* wq = wp + coi * (C_ * K_);   // wave-uniform -> s_load
#pragma unroll
                for (int k = 0; k < K_; ++k) {
                    const float wk = wq[k];
#pragma unroll
                    for (int j = 0; j < 4; ++j)
                        acc[coi][j] = fmaf(wk, xr[k + j], acc[coi][j]);
                }
            }
        }

        // ---- rotate LDS buffer ----
        if (cc < C_ / CCH_ - 1) {
            __syncthreads();
#pragma unroll
            for (int s = 0; s < 17; ++s) {
                int i = i0 + 16 * s;
                if (i < TN_ + 7) xs[ci_s][i] = pf[s];
            }
            __syncthreads();
        }
    }

    // write y + per-wave BN partials (deterministic: fixed reduction order)
    float* yrow = y + (size_t)tb * CO_ * N_;
    const int nbase = n0 + noff;
#pragma unroll
    for (int coi = 0; coi < 16; ++coi) {
        const int co = cg + coi;
        float4 v = make_float4(acc[coi][0], acc[coi][1], acc[coi][2], acc[coi][3]);
        *(float4*)(&yrow[(size_t)co * N_ + nbase]) = v;
        float s1 = (v.x + v.y) + (v.z + v.w);
        float s2 = (v.x * v.x + v.y * v.y) + (v.z * v.z + v.w * v.w);
#pragma unroll
        for (int off = 32; off > 0; off >>= 1) {
            s1 += __shfl_down(s1, off);
            s2 += __shfl_down(s2, off);
        }
        if (lane == 0) {
            psum[(size_t)(co * 2 + 0) * NBLK_ + bx] = s1;
            psum[(size_t)(co * 2 + 1) * NBLK_ + bx] = s2;
        }
    }
}

// ---------------------------------------------------------------------------
// Kernel 2: fused BN-stats + normalize + 4-step LIF.
// One block per (b, c). Each block redundantly reduces its channel's psum
// (identical fp64 order in every block -> identical scale/shift, determinism
// preserved), then applies affine + LIF over its 4096-length slice x 4 steps.
// ---------------------------------------------------------------------------
__global__ __launch_bounds__(256)
void lif_kernel(const float* __restrict__ y, const float* __restrict__ psum,
                const float* __restrict__ gamma, const float* __restrict__ beta,
                float* __restrict__ out)
{
    __shared__ double red[256];
    __shared__ float ssf[2];

    const int bx = blockIdx.x;           // 0..2047 = b*64 + c
    const int c  = bx & 63;
    const int b  = bx >> 6;
    const int tid = threadIdx.x;

    // ---- per-channel stats (same reduction order as old stats_kernel) ----
    double s1 = 0.0, s2 = 0.0;
    for (int i = tid; i < NBLK_; i += 256) {
        s1 += (double)psum[(size_t)(c * 2 + 0) * NBLK_ + i];
        s2 += (double)psum[(size_t)(c * 2 + 1) * NBLK_ + i];
    }
    red[tid] = s1;
    __syncthreads();
    for (int st = 128; st > 0; st >>= 1) {
        if (tid < st) red[tid] += red[tid + st];
        __syncthreads();
    }
    const double S1 = red[0];
    __syncthreads();
    red[tid] = s2;
    __syncthreads();
    for (int st = 128; st > 0; st >>= 1) {
        if (tid < st) red[tid] += red[tid + st];
        __syncthreads();
    }
    const double S2 = red[0];

    if (tid == 0) {
        const double M    = (double)TB_ * (double)N_;
        const double mean = S1 / M;
        const double var  = S2 / M - mean * mean;
        const double inv  = 1.0 / sqrt(var + 1e-5);
        const double g    = (double)gamma[c];
        ssf[0] = (float)(g * inv);
        ssf[1] = (float)((double)beta[c] - mean * g * inv);
    }
    __syncthreads();
    const float scale = ssf[0];
    const float shift = ssf[1];

    // ---- LIF (hard reset, tau=2, v_th=1, v_reset=0) ----
    const size_t base = ((size_t)b * CO_ + c) * N_;
    const size_t tstr = (size_t)B_ * CO_ * N_;   // timestep stride

    for (int n = tid * 4; n < N_; n += 256 * 4) {
        float4 yv[4];
        yv[0] = *(const float4*)(y + base + 0 * tstr + n);
        yv[1] = *(const float4*)(y + base + 1 * tstr + n);
        yv[2] = *(const float4*)(y + base + 2 * tstr + n);
        yv[3] = *(const float4*)(y + base + 3 * tstr + n);

        float yin[4][4] = {{yv[0].x, yv[0].y, yv[0].z, yv[0].w},
                           {yv[1].x, yv[1].y, yv[1].z, yv[1].w},
                           {yv[2].x, yv[2].y, yv[2].z, yv[2].w},
                           {yv[3].x, yv[3].y, yv[3].z, yv[3].w}};
        float so[4][4];
#pragma unroll
        for (int e = 0; e < 4; ++e) {
            float v = 0.0f;
#pragma unroll
            for (int t = 0; t < 4; ++t) {
                const float yn = fmaf(yin[t][e], scale, shift);  // BN affine
                v = v + (yn - v) * 0.5f;                          // charge
                const float s = (v >= 1.0f) ? 1.0f : 0.0f;        // fire
                so[t][e] = s;
                v = (s != 0.0f) ? 0.0f : v;                       // hard reset
            }
        }
#pragma unroll
        for (int t = 0; t < 4; ++t) {
            float4 o = make_float4(so[t][0], so[t][1], so[t][2], so[t][3]);
            *(float4*)(out + base + (size_t)t * tstr + n) = o;
        }
    }
}

// ---------------------------------------------------------------------------
extern "C" void kernel_launch(void* const* d_in, const int* in_sizes, int n_in,
                              void* d_out, int out_size, void* d_ws, size_t ws_size,
                              hipStream_t stream)
{
    const float* x     = (const float*)d_in[0];   // [4,32,64,4096]
    const float* w     = (const float*)d_in[1];   // [64,64,8]
    // d_in[2] = conv_b: cancels in BN, unused
    const float* gamma = (const float*)d_in[3];   // [64]
    const float* beta  = (const float*)d_in[4];   // [64]
    float* out = (float*)d_out;

    char* ws = (char*)d_ws;
    const size_t y_bytes = (size_t)TB_ * CO_ * N_ * sizeof(float);   // 128 MB
    float* y    = (float*)ws;
    float* psum = (float*)(ws + y_bytes);

    conv_stats_kernel<<<NBLK_, 256, 0, stream>>>(x, w, y, psum);
    lif_kernel<<<B_ * CO_, 256, 0, stream>>>(y, psum, gamma, beta, out);
}

// Round 4
// 556.990 us; speedup vs baseline: 1.4282x; 1.4282x over previous
//
#include <hip/hip_runtime.h>
#include <math.h>

#define T_    4
#define B_    32
#define C_    64
#define CO_   64
#define N_    4096
#define K_    8
#define PL_   3
#define TB_   128          // T_*B_
#define TN_   256          // n-tile per conv block
#define NT_   16           // N_/TN_
#define NBLK_ 2048         // TB_*NT_
#define CCH_  16           // ci chunk staged in LDS at a time

typedef float v2f __attribute__((ext_vector_type(2)));

// ---------------------------------------------------------------------------
// Kernel 0: repack weights into co-pairs (verbatim from round 2).
// ---------------------------------------------------------------------------
__global__ __launch_bounds__(256)
void pack_w_kernel(const float* __restrict__ w, v2f* __restrict__ wpk)
{
    int i = blockIdx.x * 256 + threadIdx.x;      // p*512 + ci*8 + k
    if (i < 32 * C_ * K_) {
        int p = i >> 9;
        int r = i & 511;
        v2f v = { w[(size_t)(2 * p) * (C_ * K_) + r],
                  w[(size_t)(2 * p + 1) * (C_ * K_) + r] };
        wpk[i] = v;
    }
}

// ---------------------------------------------------------------------------
// Kernel 1: conv + BN partials — VERBATIM round-2 version (365 us, absmax 0.0,
// VALUBusy 76%, conflicts 1.2e5). Fragile local optimum: adding live registers
// (e.g. prefetch arrays) breaks AGPR-native FMA codegen (round-3 regression,
// 648 us). Do not touch.
// ---------------------------------------------------------------------------
__global__ __launch_bounds__(256, 4)
void conv_stats_kernel(const float* __restrict__ x, const v2f* __restrict__ wpk,
                       float* __restrict__ y, float* __restrict__ psum)
{
    __shared__ float xs[CCH_][TN_ + 8];   // 16 x 264 floats = 16.9 KB

    const int bx   = blockIdx.x;
    const int tb   = bx >> 4;           // 0..127
    const int n0   = (bx & 15) * TN_;   // n tile origin
    const int tid  = threadIdx.x;
    const int lane = tid & 63;
    const int wv   = __builtin_amdgcn_readfirstlane(tid >> 6);
    const int cg   = wv * 16;           // wave's co base
    const int pg0  = wv * 8;            // wave's co-pair base
    const int noff = lane * 4;          // lane's n offset inside tile

    v2f acc[8][4];                      // [co-pair][n] packed over co
#pragma unroll
    for (int p = 0; p < 8; ++p)
#pragma unroll
        for (int j = 0; j < 4; ++j) acc[p][j] = v2f{0.0f, 0.0f};

    const float* xrow = x + (size_t)tb * C_ * N_;

    for (int cc = 0; cc < C_ / CCH_; ++cc) {
        __syncthreads();   // protect xs reuse between chunks
        // stage x[tb, cc*16 .. +15, n0-3 .. n0+259] with zero padding
        for (int idx = tid; idx < CCH_ * (TN_ + 7); idx += 256) {
            int ci = idx / (TN_ + 7);
            int i  = idx - ci * (TN_ + 7);
            int n  = n0 - PL_ + i;
            float v = 0.0f;
            if (n >= 0 && n < N_) v = xrow[(size_t)(cc * CCH_ + ci) * N_ + n];
            xs[ci][i] = v;
        }
        __syncthreads();

        for (int ci2 = 0; ci2 < CCH_; ++ci2) {
            const int ci = cc * CCH_ + ci2;
            const float4* xp = (const float4*)(&xs[ci2][noff]);
            float4 xa = xp[0], xb = xp[1], xc = xp[2];
            float xr[12] = {xa.x, xa.y, xa.z, xa.w,
                            xb.x, xb.y, xb.z, xb.w,
                            xc.x, xc.y, xc.z, xc.w};
#pragma unroll
            for (int p = 0; p < 8; ++p) {
                // wave-uniform address -> s_load_dwordx2 (x4/x8 merged)
                const v2f* wq = wpk + ((size_t)(pg0 + p) * C_ + ci) * K_;
#pragma unroll
                for (int k = 0; k < K_; ++k) {
                    const v2f wv2 = wq[k];
#pragma unroll
                    for (int j = 0; j < 4; ++j) {
                        v2f xv = { xr[k + j], xr[k + j] };   // splat
                        acc[p][j] = __builtin_elementwise_fma(wv2, xv, acc[p][j]);
                    }
                }
            }
        }
    }

    // write y + per-wave BN partials (deterministic: fixed reduction order)
    float* yrow = y + (size_t)tb * CO_ * N_;
    const int nbase = n0 + noff;
#pragma unroll
    for (int p = 0; p < 8; ++p) {
        const int co0 = cg + 2 * p;
#pragma unroll
        for (int h = 0; h < 2; ++h) {
            float4 v;
            if (h == 0) v = make_float4(acc[p][0].x, acc[p][1].x, acc[p][2].x, acc[p][3].x);
            else        v = make_float4(acc[p][0].y, acc[p][1].y, acc[p][2].y, acc[p][3].y);
            const int co = co0 + h;
            *(float4*)(&yrow[(size_t)co * N_ + nbase]) = v;
            float s1 = (v.x + v.y) + (v.z + v.w);
            float s2 = (v.x * v.x + v.y * v.y) + (v.z * v.z + v.w * v.w);
#pragma unroll
            for (int off = 32; off > 0; off >>= 1) {
                s1 += __shfl_down(s1, off);
                s2 += __shfl_down(s2, off);
            }
            if (lane == 0) {
                psum[(size_t)(co * 2 + 0) * NBLK_ + bx] = s1;
                psum[(size_t)(co * 2 + 1) * NBLK_ + bx] = s2;
            }
        }
    }
}

// ---------------------------------------------------------------------------
// Kernel 2: reduce partials -> per-channel scale/shift (deterministic, fp64).
// One block per channel; runs once (not 2048x redundantly as in round 3).
// ---------------------------------------------------------------------------
__global__ __launch_bounds__(256)
void stats_kernel(const float* __restrict__ psum,
                  const float* __restrict__ gamma, const float* __restrict__ beta,
                  float* __restrict__ ss)
{
    __shared__ double red[256];
    const int co  = blockIdx.x;
    const int tid = threadIdx.x;

    double s1 = 0.0, s2 = 0.0;
    for (int i = tid; i < NBLK_; i += 256) {
        s1 += (double)psum[(size_t)(co * 2 + 0) * NBLK_ + i];
        s2 += (double)psum[(size_t)(co * 2 + 1) * NBLK_ + i];
    }
    red[tid] = s1;
    __syncthreads();
    for (int st = 128; st > 0; st >>= 1) {
        if (tid < st) red[tid] += red[tid + st];
        __syncthreads();
    }
    const double S1 = red[0];
    __syncthreads();
    red[tid] = s2;
    __syncthreads();
    for (int st = 128; st > 0; st >>= 1) {
        if (tid < st) red[tid] += red[tid + st];
        __syncthreads();
    }
    const double S2 = red[0];

    if (tid == 0) {
        const double M    = (double)TB_ * (double)N_;
        const double mean = S1 / M;
        const double var  = S2 / M - mean * mean;
        const double inv  = 1.0 / sqrt(var + 1e-5);
        const double g    = (double)gamma[co];
        ss[co * 2 + 0] = (float)(g * inv);
        ss[co * 2 + 1] = (float)((double)beta[co] - mean * g * inv);
    }
}

// ---------------------------------------------------------------------------
// Kernel 3: normalize + 4-step LIF, fully flat: 8192 blocks, each thread owns
// exactly one float4 across all 4 timesteps (no loops -> max memory
// parallelism). LIF math identical to rounds 1-3.
// ---------------------------------------------------------------------------
__global__ __launch_bounds__(256)
void lif_kernel(const float* __restrict__ y, const float* __restrict__ ss,
                float* __restrict__ out)
{
    const int bx = blockIdx.x;           // b(32) x c(64) x nc(4)
    const int nc = bx & 3;
    const int c  = (bx >> 2) & 63;
    const int b  = bx >> 8;
    const float scale = ss[c * 2 + 0];
    const float shift = ss[c * 2 + 1];
    const size_t base = ((size_t)b * CO_ + c) * N_ + nc * 1024 + threadIdx.x * 4;
    const size_t tstr = (size_t)B_ * CO_ * N_;   // timestep stride

    float4 yv[4];
#pragma unroll
    for (int t = 0; t < 4; ++t)
        yv[t] = *(const float4*)(y + base + (size_t)t * tstr);

    float yin[4][4] = {{yv[0].x, yv[0].y, yv[0].z, yv[0].w},
                       {yv[1].x, yv[1].y, yv[1].z, yv[1].w},
                       {yv[2].x, yv[2].y, yv[2].z, yv[2].w},
                       {yv[3].x, yv[3].y, yv[3].z, yv[3].w}};
    float so[4][4];
#pragma unroll
    for (int e = 0; e < 4; ++e) {
        float v = 0.0f;
#pragma unroll
        for (int t = 0; t < 4; ++t) {
            const float yn = fmaf(yin[t][e], scale, shift);  // BN affine
            v = v + (yn - v) * 0.5f;                          // charge
            const float s = (v >= 1.0f) ? 1.0f : 0.0f;        // fire
            so[t][e] = s;
            v = (s != 0.0f) ? 0.0f : v;                       // hard reset
        }
    }
#pragma unroll
    for (int t = 0; t < 4; ++t) {
        float4 o = make_float4(so[t][0], so[t][1], so[t][2], so[t][3]);
        *(float4*)(out + base + (size_t)t * tstr) = o;
    }
}

// ---------------------------------------------------------------------------
extern "C" void kernel_launch(void* const* d_in, const int* in_sizes, int n_in,
                              void* d_out, int out_size, void* d_ws, size_t ws_size,
                              hipStream_t stream)
{
    const float* x     = (const float*)d_in[0];   // [4,32,64,4096]
    const float* w     = (const float*)d_in[1];   // [64,64,8]
    // d_in[2] = conv_b: cancels in BN, unused
    const float* gamma = (const float*)d_in[3];   // [64]
    const float* beta  = (const float*)d_in[4];   // [64]
    float* out = (float*)d_out;

    char* ws = (char*)d_ws;
    const size_t y_bytes    = (size_t)TB_ * CO_ * N_ * sizeof(float);   // 128 MB
    const size_t psum_bytes = (size_t)CO_ * 2 * NBLK_ * sizeof(float);  // 1 MB
    float* y    = (float*)ws;
    float* psum = (float*)(ws + y_bytes);
    float* ss   = (float*)(ws + y_bytes + psum_bytes);
    v2f*   wpk  = (v2f*)(ws + y_bytes + psum_bytes + 512);

    pack_w_kernel<<<64, 256, 0, stream>>>(w, wpk);
    conv_stats_kernel<<<NBLK_, 256, 0, stream>>>(x, wpk, y, psum);
    stats_kernel<<<CO_, 256, 0, stream>>>(psum, gamma, beta, ss);
    lif_kernel<<<B_ * CO_ * 4, 256, 0, stream>>>(y, ss, out);
}